// Round 2
// baseline (1111.982 us; speedup 1.0000x reference)
//
#include <hip/hip_runtime.h>

namespace {
constexpr int NB = 1024;      // nodes
constexpr int NC = 128;       // channels
constexpr int NL = 16;        // coupling dim
constexpr int NE = 10;        // elements
constexpr int NOUT = 4 * NC;  // 512 output cols per node
constexpr int NCH = 4;        // channels per block (U3 amortization factor)
constexpr int NTHREADS = 256; // 4 waves; wave w <-> channel cg4+w
constexpr int SLOTS = 128;    // node slots per chunk (2 per lane)
}

// dynamic 16-way select with only static register indexing (4 cmp + 15 cndmask)
__device__ __forceinline__ float sel16(const float (&v)[NL], int i) {
    float t8[8], t4[4], t2[2];
#pragma unroll
    for (int k = 0; k < 8; ++k) t8[k] = (i & 1) ? v[2 * k + 1] : v[2 * k];
#pragma unroll
    for (int k = 0; k < 4; ++k) t4[k] = (i & 2) ? t8[2 * k + 1] : t8[2 * k];
#pragma unroll
    for (int k = 0; k < 2; ++k) t2[k] = (i & 4) ? t4[2 * k + 1] : t4[2 * k];
    return (i & 8) ? t2[1] : t2[0];
}

// One pass = one output irrep slice (0e, or one 1o w-slice).
// stage W -> build uw3[c][256][16], uw2[c][256], uw1[c][16] in LDS -> node phase.
// Node math per node: out = sum_i x_i * ( uw1[i] + sum_j x_j * ( uw2[i*16+j]
//                       + sum_m uw3[(i*16+j)*16+m] * x_m ) )
template <int P3, int P2>
__device__ __forceinline__ void run_pass(
    const float* __restrict__ U3p,   // [4096, P3]
    const float* __restrict__ U2p,   // [256, P2]
    const float* __restrict__ U1p,   // [16]
    const float* __restrict__ W3e,   // W3 + e*P3*NC + cg4 ; index k*NC + cl
    const float* __restrict__ W2e,   // W2 + e*P2*NC + cg4
    const float* __restrict__ W1e,   // W1 + e*NC + cg4 ; index cl
    float* __restrict__ s_uw3, float* __restrict__ s_uw2,
    float* __restrict__ s_uw1, float* __restrict__ s_w3, float* __restrict__ s_w2,
    const float (&xv0)[NL], const float (&xv1)[NL],
    bool v0, bool v1, int b0, int b1,
    float* __restrict__ out, int col,
    int tid, int w)
{
    // ---- stage per-channel W slices (tiny) ----
    if (tid < P3 * NCH) {
        s_w3[tid] = W3e[(tid >> 2) * NC + (tid & 3)];
    } else if (tid >= 148 && tid < 148 + P2 * NCH) {
        const int t = tid - 148;
        s_w2[t] = W2e[(t >> 2) * NC + (t & 3)];
    } else if (tid >= 176 && tid < 176 + NCH * NL) {
        const int t = tid - 176;
        s_uw1[t] = U1p[t & 15] * W1e[t >> 4];
    }
    __syncthreads();

    // ---- build uw3 for all 4 channels (U3 read once per block) ----
    for (int g = tid; g < 4096; g += NTHREADS) {
        const float* up = U3p + (size_t)g * P3;
        float u[P3];
#pragma unroll
        for (int k = 0; k < P3; ++k) u[k] = up[k];
        float a0 = 0.f, a1 = 0.f, a2 = 0.f, a3 = 0.f;
#pragma unroll
        for (int k = 0; k < P3; ++k) {
            const float4 wv = reinterpret_cast<const float4*>(s_w3)[k];
            a0 = fmaf(u[k], wv.x, a0); a1 = fmaf(u[k], wv.y, a1);
            a2 = fmaf(u[k], wv.z, a2); a3 = fmaf(u[k], wv.w, a3);
        }
        s_uw3[0 * 4096 + g] = a0; s_uw3[1 * 4096 + g] = a1;
        s_uw3[2 * 4096 + g] = a2; s_uw3[3 * 4096 + g] = a3;
    }
    {   // uw2: exactly one q per thread
        const float* up = U2p + tid * P2;
        float a0 = 0.f, a1 = 0.f, a2 = 0.f, a3 = 0.f;
#pragma unroll
        for (int k = 0; k < P2; ++k) {
            const float4 wv = reinterpret_cast<const float4*>(s_w2)[k];
            const float u = up[k];
            a0 = fmaf(u, wv.x, a0); a1 = fmaf(u, wv.y, a1);
            a2 = fmaf(u, wv.z, a2); a3 = fmaf(u, wv.w, a3);
        }
        s_uw2[0 * 256 + tid] = a0; s_uw2[1 * 256 + tid] = a1;
        s_uw2[2 * 256 + tid] = a2; s_uw2[3 * 256 + tid] = a3;
    }
    __syncthreads();

    // ---- node phase: wave w reads channel w's uw tiles (broadcast ds_reads) ----
    const float* uw3c = s_uw3 + w * 4096;
    const float* uw2c = s_uw2 + w * 256;
    const float* uw1c = s_uw1 + w * NL;
    float acc0 = 0.f, acc1 = 0.f;
    for (int i = 0; i < NL; ++i) {
        const float xi0 = sel16(xv0, i);
        const float xi1 = sel16(xv1, i);
        const float* rowb = uw3c + i * 256;
        const float* u2b  = uw2c + i * 16;
        float t0 = 0.f, t1 = 0.f;
#pragma unroll
        for (int j = 0; j < NL; ++j) {
            float r[NL];
            reinterpret_cast<float4*>(r)[0] = reinterpret_cast<const float4*>(rowb + j * 16)[0];
            reinterpret_cast<float4*>(r)[1] = reinterpret_cast<const float4*>(rowb + j * 16)[1];
            reinterpret_cast<float4*>(r)[2] = reinterpret_cast<const float4*>(rowb + j * 16)[2];
            reinterpret_cast<float4*>(r)[3] = reinterpret_cast<const float4*>(rowb + j * 16)[3];
            float y0 = u2b[j], y1 = y0;
#pragma unroll
            for (int m = 0; m < NL; ++m) {
                y0 = fmaf(r[m], xv0[m], y0);
                y1 = fmaf(r[m], xv1[m], y1);
            }
            t0 = fmaf(xv0[j], y0, t0);
            t1 = fmaf(xv1[j], y1, t1);
        }
        acc0 = fmaf(xi0, t0, acc0);
        acc1 = fmaf(xi1, t1, acc1);
    }
#pragma unroll
    for (int i = 0; i < NL; ++i) {
        const float u1 = uw1c[i];
        acc0 = fmaf(u1, xv0[i], acc0);
        acc1 = fmaf(u1, xv1[i], acc1);
    }
    if (v0) out[(size_t)b0 * NOUT + col] = acc0;
    if (v1) out[(size_t)b1 * NOUT + col] = acc1;
    __syncthreads();   // uw/sW buffers free for next pass
}

__global__ void __launch_bounds__(NTHREADS, 2) symcon_kernel(
    const float* __restrict__ x, const float* __restrict__ y,
    const float* __restrict__ U1_0e, const float* __restrict__ U2_0e,
    const float* __restrict__ U3_0e,
    const float* __restrict__ W1_0e, const float* __restrict__ W2_0e,
    const float* __restrict__ W3_0e,
    const float* __restrict__ U1_1o, const float* __restrict__ U2_1o,
    const float* __restrict__ U3_1o,
    const float* __restrict__ W1_1o, const float* __restrict__ W2_1o,
    const float* __restrict__ W3_1o,
    float* __restrict__ out)
{
    __shared__ __align__(16) float s_uw3[NCH * 4096];  // 64 KiB
    __shared__ __align__(16) float s_uw2[NCH * 256];   // 4 KiB
    __shared__ __align__(16) float s_uw1[NCH * NL];
    __shared__ __align__(16) float s_w3[37 * NCH];
    __shared__ __align__(16) float s_w2[6 * NCH];
    __shared__ int s_nid[NB];                          // 4 KiB
    __shared__ int s_cnt;

    const int tid = threadIdx.x;
    const int bid = blockIdx.x;
    const int e   = bid % NE;
    const int cg4 = (bid / NE) * NCH;
    const int w    = tid >> 6;
    const int lane = tid & 63;
    const int cch  = cg4 + w;      // this wave's channel

    // ---- gather node list for element e ----
    if (tid == 0) s_cnt = 0;
    __syncthreads();
    for (int b = tid; b < NB; b += NTHREADS)
        if (y[b * NE + e] > 0.5f) s_nid[atomicAdd(&s_cnt, 1)] = b;
    __syncthreads();
    const int nn = s_cnt;
    if (nn == 0) return;

    const float* W3e0 = W3_0e + (size_t)e * 23 * NC + cg4;
    const float* W2e0 = W2_0e + (size_t)e * 4 * NC + cg4;
    const float* W1e0 = W1_0e + (size_t)e * NC + cg4;
    const float* W3e1 = W3_1o + (size_t)e * 37 * NC + cg4;
    const float* W2e1 = W2_1o + (size_t)e * 6 * NC + cg4;
    const float* W1e1 = W1_1o + (size_t)e * NC + cg4;

    for (int ns = 0; ns < nn; ns += SLOTS) {
        const int sA = ns + lane, sB = ns + 64 + lane;
        const bool vA = sA < nn, vB = sB < nn;
        const int b0 = s_nid[vA ? sA : 0];
        const int b1 = s_nid[vB ? sB : 0];
        float xv0[NL], xv1[NL];
        const float4* xp0 = reinterpret_cast<const float4*>(x + ((size_t)b0 * NC + cch) * NL);
        const float4* xp1 = reinterpret_cast<const float4*>(x + ((size_t)b1 * NC + cch) * NL);
#pragma unroll
        for (int v4 = 0; v4 < 4; ++v4) {
            reinterpret_cast<float4*>(xv0)[v4] = xp0[v4];
            reinterpret_cast<float4*>(xv1)[v4] = xp1[v4];
        }

        run_pass<23, 4>(U3_0e, U2_0e, U1_0e, W3e0, W2e0, W1e0,
                        s_uw3, s_uw2, s_uw1, s_w3, s_w2,
                        xv0, xv1, vA, vB, b0, b1, out, cch, tid, w);
        for (int wp = 0; wp < 3; ++wp) {
            run_pass<37, 6>(U3_1o + (size_t)wp * 4096 * 37,
                            U2_1o + wp * 256 * 6,
                            U1_1o + wp * NL,
                            W3e1, W2e1, W1e1,
                            s_uw3, s_uw2, s_uw1, s_w3, s_w2,
                            xv0, xv1, vA, vB, b0, b1, out,
                            NC + cch * 3 + wp, tid, w);
        }
    }
}

extern "C" void kernel_launch(void* const* d_in, const int* in_sizes, int n_in,
                              void* d_out, int out_size, void* d_ws, size_t ws_size,
                              hipStream_t stream) {
    const float* x     = (const float*)d_in[0];
    const float* y     = (const float*)d_in[1];
    const float* U1_0e = (const float*)d_in[2];
    const float* U2_0e = (const float*)d_in[3];
    const float* U3_0e = (const float*)d_in[4];
    const float* W1_0e = (const float*)d_in[5];
    const float* W2_0e = (const float*)d_in[6];
    const float* W3_0e = (const float*)d_in[7];
    const float* U1_1o = (const float*)d_in[8];
    const float* U2_1o = (const float*)d_in[9];
    const float* U3_1o = (const float*)d_in[10];
    const float* W1_1o = (const float*)d_in[11];
    const float* W2_1o = (const float*)d_in[12];
    const float* W3_1o = (const float*)d_in[13];
    float* out = (float*)d_out;

    hipLaunchKernelGGL(symcon_kernel, dim3(NE * (NC / NCH)), dim3(NTHREADS), 0, stream,
                       x, y, U1_0e, U2_0e, U3_0e, W1_0e, W2_0e, W3_0e,
                       U1_1o, U2_1o, U3_1o, W1_1o, W2_1o, W3_1o, out);
}

// Round 3
// 217.601 us; speedup vs baseline: 5.1102x; 5.1102x over previous
//
#include <hip/hip_runtime.h>

namespace {
constexpr int NB = 1024;      // nodes
constexpr int NC = 128;       // channels
constexpr int NL = 16;        // coupling dim
constexpr int NE = 10;        // elements
constexpr int NOUT = 4 * NC;  // 512 output cols per node
constexpr int NCH = 2;        // channels per block
constexpr int NTHREADS = 256; // 4 waves: waves {0,1}->ch0, {2,3}->ch1
constexpr int RP = 17;        // uw3 LDS row pad (17 coprime 32, b32 conflict-free)
constexpr int P3_0 = 23, P2_0 = 4, P3_1 = 37, P2_1 = 6;
constexpr int QRP = 256 * RP;              // per-channel uw3 LDS floats
constexpr int T0 = 4096 * P3_0;            // 0e transposed elems
constexpr int TRANS_ELEMS = 4096 * (P3_0 + 3 * P3_1);  // 548864
}

// U3 -> ws in [k][g] layout (g fastest) so the build phase reads coalesced.
__global__ void transpose_u3(const float* __restrict__ U3_0e,
                             const float* __restrict__ U3_1o,
                             float* __restrict__ ws) {
    const int n = blockIdx.x * blockDim.x + threadIdx.x;
    if (n < T0) {
        const int k = n >> 12, g = n & 4095;
        ws[n] = U3_0e[g * P3_0 + k];
    } else if (n < TRANS_ELEMS) {
        const int m = n - T0;
        const int wp = m / (P3_1 * 4096);
        const int rem = m - wp * (P3_1 * 4096);
        const int k = rem >> 12, g = rem & 4095;
        ws[n] = U3_1o[(size_t)(wp * 4096 + g) * P3_1 + k];
    }
}

// One pass = one output irrep slice.
// out[b] = sum_i x_i*( uw1[i] + sum_j x_j*( uw2[i*16+j] + sum_m uw3[(i*16+j)*16+m]*x_m ) )
// Lane owns q = lane+64a (a=0..3): j = lane&15, i = (lane>>4)+4a.
template <int P3, int P2>
__device__ __forceinline__ void run_pass(
    const float* __restrict__ U3t,   // transposed [k][4096] (or nullptr)
    const float* __restrict__ U3p,   // original [4096][P3] (fallback)
    const float* __restrict__ U2p,   // [256][P2]
    const float* __restrict__ U1p,   // [16]
    const float* __restrict__ W3e,   // + e*P3*NC + cg ; [k*NC + ch]
    const float* __restrict__ W2e,
    const float* __restrict__ W1e,   // + e*NC + cg ; [ch]
    float* __restrict__ s_uw3, float* __restrict__ s_uw2,
    float* __restrict__ s_uw1, float* __restrict__ s_w3, float* __restrict__ s_w2,
    const int* __restrict__ s_nid, int nn,
    const float* __restrict__ x, int cg,
    float* __restrict__ out, int col_base, int col_mul, int col_add,
    int tid)
{
    // ---- stage W slices ----
    if (tid < 2 * P3) {
        s_w3[tid] = W3e[(tid >> 1) * NC + (tid & 1)];
    } else if (tid >= 128 && tid < 128 + 2 * P2) {
        const int t = tid - 128;
        s_w2[t] = W2e[(t >> 1) * NC + (t & 1)];
    } else if (tid >= 160 && tid < 192) {
        const int t = tid - 160;                 // ch = t>>4, i = t&15
        s_uw1[t] = U1p[t & 15] * W1e[t >> 4];
    }
    __syncthreads();

    // ---- build uw3 (both channels) + uw2 ----
    if (U3t) {
        // coalesced: thread owns g = 4*tid + 1024*r + gi
#pragma unroll 1
        for (int r = 0; r < 4; ++r) {
            float a0[4] = {0.f, 0.f, 0.f, 0.f}, a1[4] = {0.f, 0.f, 0.f, 0.f};
#pragma unroll 4
            for (int k = 0; k < P3; ++k) {
                const float4 u = *reinterpret_cast<const float4*>(
                    U3t + ((size_t)k << 12) + 4 * tid + (r << 10));
                const float2 wk = *reinterpret_cast<const float2*>(&s_w3[2 * k]);
                a0[0] = fmaf(u.x, wk.x, a0[0]); a1[0] = fmaf(u.x, wk.y, a1[0]);
                a0[1] = fmaf(u.y, wk.x, a0[1]); a1[1] = fmaf(u.y, wk.y, a1[1]);
                a0[2] = fmaf(u.z, wk.x, a0[2]); a1[2] = fmaf(u.z, wk.y, a1[2]);
                a0[3] = fmaf(u.w, wk.x, a0[3]); a1[3] = fmaf(u.w, wk.y, a1[3]);
            }
            const int q = (tid >> 2) + 64 * r;
            const int mb = 4 * (tid & 3);
#pragma unroll
            for (int gi = 0; gi < 4; ++gi) {
                s_uw3[q * RP + mb + gi] = a0[gi];
                s_uw3[QRP + q * RP + mb + gi] = a1[gi];
            }
        }
    } else {
        // fallback: row-scalar reads of original U3
#pragma unroll 1
        for (int r = 0; r < 16; ++r) {
            const int g = tid + 256 * r;
            const float* up = U3p + (size_t)g * P3;
            float b0 = 0.f, b1 = 0.f;
#pragma unroll 4
            for (int k = 0; k < P3; ++k) {
                const float u = up[k];
                b0 = fmaf(u, s_w3[2 * k], b0);
                b1 = fmaf(u, s_w3[2 * k + 1], b1);
            }
            const int q = g >> 4, mm = g & 15;
            s_uw3[q * RP + mm] = b0;
            s_uw3[QRP + q * RP + mm] = b1;
        }
    }
    {   // uw2: one q per thread
        const float* up = U2p + tid * P2;
        float c0 = 0.f, c1 = 0.f;
#pragma unroll
        for (int k = 0; k < P2; ++k) {
            const float u = up[k];
            c0 = fmaf(u, s_w2[2 * k], c0);
            c1 = fmaf(u, s_w2[2 * k + 1], c1);
        }
        s_uw2[tid] = c0;
        s_uw2[256 + tid] = c1;
    }
    __syncthreads();

    // ---- fragment load: register-resident uw3 rows (once per pass) ----
    const int lane = tid & 63;
    const int w = tid >> 6;
    const int ch = w >> 1;                 // waves {0,1}->ch0, {2,3}->ch1
    const int cc = cg + ch;                // absolute channel
    const int half = ch * QRP;
    float r3[4][NL];
    float r2[4];
#pragma unroll
    for (int a = 0; a < 4; ++a) {
        const int q = lane + 64 * a;
#pragma unroll
        for (int m = 0; m < NL; ++m) r3[a][m] = s_uw3[half + q * RP + m];
        r2[a] = s_uw2[ch * 256 + q];
    }
    const int jj = lane & 15;
    const int i0 = lane >> 4;
    const float u1j = s_uw1[ch * NL + jj] * 0.25f;
    const int col = col_base + cc * col_mul + col_add;

    // ---- node loop: 2 nodes per wave per iter; wave pair splits slots ----
    for (int s0 = (w & 1) * 2; s0 < nn; s0 += 4) {
        const bool v1 = (s0 + 1) < nn;
        const int b0 = s_nid[s0];
        const int b1 = s_nid[v1 ? s0 + 1 : s0];
        const float* xr0 = x + ((size_t)b0 * NC + cc) * NL;
        const float* xr1 = x + ((size_t)b1 * NC + cc) * NL;
        // per-lane dynamic x picks -> VMEM (same cache line), not register indexing
        const float xj0 = xr0[jj], xj1 = xr1[jj];
        float xi0[4], xi1[4];
#pragma unroll
        for (int a = 0; a < 4; ++a) { xi0[a] = xr0[i0 + 4 * a]; xi1[a] = xr1[i0 + 4 * a]; }
        float xv0[NL], xv1[NL];
#pragma unroll
        for (int v4 = 0; v4 < 4; ++v4) {
            reinterpret_cast<float4*>(xv0)[v4] = reinterpret_cast<const float4*>(xr0)[v4];
            reinterpret_cast<float4*>(xv1)[v4] = reinterpret_cast<const float4*>(xr1)[v4];
        }
        float acc0 = u1j * xj0;
        float acc1 = u1j * xj1;
#pragma unroll
        for (int a = 0; a < 4; ++a) {
            float y0 = r2[a], y1 = r2[a];
#pragma unroll
            for (int m = 0; m < NL; ++m) {
                y0 = fmaf(r3[a][m], xv0[m], y0);
                y1 = fmaf(r3[a][m], xv1[m], y1);
            }
            acc0 = fmaf(xi0[a] * xj0, y0, acc0);
            acc1 = fmaf(xi1[a] * xj1, y1, acc1);
        }
#pragma unroll
        for (int off = 32; off > 0; off >>= 1) {
            acc0 += __shfl_xor(acc0, off, 64);
            acc1 += __shfl_xor(acc1, off, 64);
        }
        if (lane == 0) out[(size_t)b0 * NOUT + col] = acc0;
        if (lane == 1 && v1) out[(size_t)b1 * NOUT + col] = acc1;
    }
    __syncthreads();   // LDS free for next pass
}

__global__ void __launch_bounds__(NTHREADS, 3) symcon_kernel(
    const float* __restrict__ x, const float* __restrict__ y,
    const float* __restrict__ U1_0e, const float* __restrict__ U2_0e,
    const float* __restrict__ U3_0e,
    const float* __restrict__ W1_0e, const float* __restrict__ W2_0e,
    const float* __restrict__ W3_0e,
    const float* __restrict__ U1_1o, const float* __restrict__ U2_1o,
    const float* __restrict__ U3_1o,
    const float* __restrict__ W1_1o, const float* __restrict__ W2_1o,
    const float* __restrict__ W3_1o,
    const float* __restrict__ U3t,    // transposed ws (or nullptr)
    float* __restrict__ out)
{
    __shared__ __align__(16) float s_uw3[NCH * QRP];   // 34.8 KiB
    __shared__ __align__(16) float s_uw2[NCH * 256];
    __shared__ __align__(16) float s_uw1[NCH * NL];
    __shared__ __align__(16) float s_w3[2 * P3_1 + 2];
    __shared__ __align__(16) float s_w2[2 * P2_1 + 2];
    __shared__ int s_nid[NB];
    __shared__ int s_cnt;

    const int tid = threadIdx.x;
    const int bid = blockIdx.x;
    const int e = bid % NE;
    const int cg = (bid / NE) * NCH;

    if (tid == 0) s_cnt = 0;
    __syncthreads();
    for (int b = tid; b < NB; b += NTHREADS)
        if (y[b * NE + e] > 0.5f) s_nid[atomicAdd(&s_cnt, 1)] = b;
    __syncthreads();
    const int nn = s_cnt;
    if (nn == 0) return;

    // pass 0e -> col = c
    run_pass<P3_0, P2_0>(U3t, U3_0e, U2_0e, U1_0e,
                         W3_0e + (size_t)e * P3_0 * NC + cg,
                         W2_0e + (size_t)e * P2_0 * NC + cg,
                         W1_0e + (size_t)e * NC + cg,
                         s_uw3, s_uw2, s_uw1, s_w3, s_w2,
                         s_nid, nn, x, cg, out, 0, 1, 0, tid);
    // passes 1o wp -> col = 128 + 3c + wp
    for (int wp = 0; wp < 3; ++wp) {
        const float* t1 = U3t ? U3t + (size_t)4096 * (P3_0 + wp * P3_1) : nullptr;
        run_pass<P3_1, P2_1>(t1, U3_1o + (size_t)wp * 4096 * P3_1,
                             U2_1o + wp * 256 * P2_1,
                             U1_1o + wp * NL,
                             W3_1o + (size_t)e * P3_1 * NC + cg,
                             W2_1o + (size_t)e * P2_1 * NC + cg,
                             W1_1o + (size_t)e * NC + cg,
                             s_uw3, s_uw2, s_uw1, s_w3, s_w2,
                             s_nid, nn, x, cg, out, NC, 3, wp, tid);
    }
}

extern "C" void kernel_launch(void* const* d_in, const int* in_sizes, int n_in,
                              void* d_out, int out_size, void* d_ws, size_t ws_size,
                              hipStream_t stream) {
    const float* x     = (const float*)d_in[0];
    const float* y     = (const float*)d_in[1];
    const float* U1_0e = (const float*)d_in[2];
    const float* U2_0e = (const float*)d_in[3];
    const float* U3_0e = (const float*)d_in[4];
    const float* W1_0e = (const float*)d_in[5];
    const float* W2_0e = (const float*)d_in[6];
    const float* W3_0e = (const float*)d_in[7];
    const float* U1_1o = (const float*)d_in[8];
    const float* U2_1o = (const float*)d_in[9];
    const float* U3_1o = (const float*)d_in[10];
    const float* W1_1o = (const float*)d_in[11];
    const float* W2_1o = (const float*)d_in[12];
    const float* W3_1o = (const float*)d_in[13];
    float* out = (float*)d_out;

    const bool use_t = ws_size >= (size_t)TRANS_ELEMS * sizeof(float);
    float* U3t = use_t ? (float*)d_ws : nullptr;
    if (use_t) {
        hipLaunchKernelGGL(transpose_u3, dim3((TRANS_ELEMS + 255) / 256),
                           dim3(256), 0, stream, U3_0e, U3_1o, U3t);
    }
    hipLaunchKernelGGL(symcon_kernel, dim3(NE * (NC / NCH)), dim3(NTHREADS), 0, stream,
                       x, y, U1_0e, U2_0e, U3_0e, W1_0e, W2_0e, W3_0e,
                       U1_1o, U2_1o, U3_1o, W1_1o, W2_1o, W3_1o, U3t, out);
}